// Round 16
// baseline (474.052 us; speedup 1.0000x reference)
//
#include <hip/hip_runtime.h>
#include <hip/hip_fp16.h>
#include <math.h>
#include <string.h>

// ---------------- constants ----------------
constexpr int HDIM = 128;     // hidden width
constexpr int RB   = 136;     // fp16 row stride for hcat/z (272B) -- empirically fastest gather
constexpr int ZS   = 168;     // LDS z-tile stride (336B)
constexpr float BN_INV = 0.99999500003749980f; // 1/sqrt(1+1e-5)

typedef _Float16 half8v __attribute__((ext_vector_type(8)));  // 8 fp16 (4 VGPR)
typedef __attribute__((ext_vector_type(4))) float float4v;    // MFMA accum

// packed fp16 ops on raw u32 pairs (VOP3P)
__device__ __forceinline__ unsigned pkmax(unsigned a, unsigned b) {
  unsigned r;
  asm volatile("v_pk_max_f16 %0, %1, %2" : "=v"(r) : "v"(a), "v"(b));
  return r;
}
__device__ __forceinline__ unsigned pkadd(unsigned a, unsigned b) {
  unsigned r;
  asm volatile("v_pk_add_f16 %0, %1, %2" : "=v"(r) : "v"(a), "v"(b));
  return r;
}

__device__ __forceinline__ float us2f(unsigned short u) { __half h; memcpy(&h, &u, 2); return __half2float(h); }
__device__ __forceinline__ unsigned short f2us(float f) {
  __half h = __float2half(f); unsigned short u; memcpy(&u, &h, 2); return u;
}

// monotone float<->uint encoding for atomic max on floats
__device__ __forceinline__ unsigned encf(float f) {
  unsigned u = __float_as_uint(f);
  return (u & 0x80000000u) ? ~u : (u | 0x80000000u);
}
__device__ __forceinline__ float decf(unsigned u) {
  return (u & 0x80000000u) ? __uint_as_float(u ^ 0x80000000u) : __uint_as_float(~u);
}

// m204 bijective XCD swizzle (heuristic; wrong mapping = only lost locality)
__device__ __forceinline__ int xcd_swz(int bid, int nwg) {
  int q = nwg >> 3, r = nwg & 7;
  int xcd = bid & 7, idx = bid >> 3;
  int base = (xcd < r) ? xcd * (q + 1) : r * (q + 1) + (xcd - r) * q;
  return base + idx;
}

// ================= CSR build (bucket-local, LDS-atomic) =================
// (bucket histogram is fused into k_prep)
__global__ __launch_bounds__(256) void k_bscan(
    const int* __restrict__ bcnt, int* __restrict__ bbase, int* __restrict__ gcur,
    int nbkt, int E) {
  __shared__ int s[256];
  int tid = threadIdx.x;
  int v = (tid < nbkt) ? bcnt[tid] : 0;
  s[tid] = v;
  __syncthreads();
  for (int off = 1; off < 256; off <<= 1) {
    int t = (tid >= off) ? s[tid - off] : 0;
    __syncthreads();
    s[tid] += t;
    __syncthreads();
  }
  if (tid < nbkt) {
    int e = s[tid] - v;
    bbase[tid] = e;
    gcur[tid] = e;
  }
  if (tid == 0) bbase[nbkt] = E;
}

// phase A: 8192-edge chunks (64KB sbuf, 2 blocks/CU) -> longer coalesced runs on flush
__global__ __launch_bounds__(256) void k_bscatter(
    const int* __restrict__ ei, int* __restrict__ gcur,
    unsigned long long* __restrict__ sorted, int E, int shift, int nbkt) {
  __shared__ int hcnt[256];
  __shared__ int hstart[256];
  __shared__ int gbase[256];
  __shared__ unsigned long long sbuf[8192];  // 64 KB

  const int tid = threadIdx.x;
  const int base = blockIdx.x * 8192;
  const int validCount = min(8192, E - base);

  hcnt[tid] = 0;
  __syncthreads();

  int sArr[32], dArr[32];
#pragma unroll
  for (int k = 0; k < 32; ++k) {
    int e = base + k * 256 + tid;
    if (e < E) {
      sArr[k] = ei[e];
      dArr[k] = ei[E + e];
      atomicAdd(&hcnt[dArr[k] >> shift], 1);
    } else {
      sArr[k] = -1; dArr[k] = -1;
    }
  }
  __syncthreads();

  {
    int v = hcnt[tid];
    __shared__ int sc[256];
    sc[tid] = v;
    __syncthreads();
    for (int off = 1; off < 256; off <<= 1) {
      int t = (tid >= off) ? sc[tid - off] : 0;
      __syncthreads();
      sc[tid] += t;
      __syncthreads();
    }
    hstart[tid] = sc[tid] - v;
    if (tid < nbkt && v > 0) gbase[tid] = atomicAdd(&gcur[tid], v);
    hcnt[tid] = sc[tid] - v;
  }
  __syncthreads();

#pragma unroll
  for (int k = 0; k < 32; ++k) {
    if (dArr[k] >= 0) {
      int b = dArr[k] >> shift;
      int p = atomicAdd(&hcnt[b], 1);
      sbuf[p] = ((unsigned long long)(unsigned)dArr[k] << 32) | (unsigned)sArr[k];
    }
  }
  __syncthreads();

  for (int p = tid; p < validCount; p += 256) {
    unsigned long long v = sbuf[p];
    int b = (int)(v >> 32) >> shift;
    sorted[(size_t)gbase[b] + (p - hstart[b])] = v;
  }
}

// phase B: one 512-thread block per bucket -> rowptr + eidx scatter (cursors in LDS)
__global__ __launch_bounds__(512) void k_bcsr(
    const unsigned long long* __restrict__ sorted, const int* __restrict__ bbase,
    int* __restrict__ rowptr, int* __restrict__ eidx,
    int shift, int nbkt, int N, int E) {
  __shared__ int cnt[512];
  __shared__ int sc[512];
  const int b = blockIdx.x, tid = threadIdx.x;
  const int nodeBase = b << shift;
  const int nodesHere = min(512, N - nodeBase);
  const int lo = bbase[b], hi = bbase[b + 1];

  cnt[tid] = 0;
  __syncthreads();
  for (int i = lo + tid; i < hi; i += 512) {
    int d = (int)(sorted[i] >> 32);
    atomicAdd(&cnt[d - nodeBase], 1);
  }
  __syncthreads();
  int v = cnt[tid];
  sc[tid] = v;
  __syncthreads();
  for (int off = 1; off < 512; off <<= 1) {
    int t = (tid >= off) ? sc[tid - off] : 0;
    __syncthreads();
    sc[tid] += t;
    __syncthreads();
  }
  int excl = sc[tid] - v;
  if (tid < nodesHere) rowptr[nodeBase + tid] = lo + excl;
  cnt[tid] = excl;  // reset as running cursor
  if (b == nbkt - 1 && tid == 0) rowptr[N] = E;
  __syncthreads();
  for (int i = lo + tid; i < hi; i += 512) {
    unsigned long long vv = sorted[i];
    int d = (int)(vv >> 32);
    int s = (int)(vv & 0xFFFFFFFFu);
    int p = atomicAdd(&cnt[d - nodeBase], 1);
    eidx[lo + p] = s;
  }
}

// ================= merged prep (+ fused bucket histogram) =================
struct PrepArgs {
  const float *x, *pos;
  const float *w01, *w11, *w21, *w02, *w12, *w22;
  const float *b01, *g01, *e01, *b02, *g02, *e02;
  const float *b11, *g11, *e11, *b12, *g12, *e12;
  const float *b21, *g21, *e21, *b22, *g22, *e22;
  const int *ei;
  int *bcnt;
  unsigned short *h0;    // [N][RB] interleaved
  unsigned short *Wt;
  unsigned *pooled;
  float *Ep;             // [3][2][2][128]
  int N, GH, E, shift, nbkt, chunks;
};

__global__ __launch_bounds__(256) void k_prep(PrepArgs a) {
  __shared__ int hb[256];
  const int tid = threadIdx.x;
  const int gtid = blockIdx.x * 256 + tid;

  // ---- fused CSR bucket histogram (blocks < chunks; 4096 edges/block) ----
  if (blockIdx.x < a.chunks) {
    hb[tid] = 0;
    __syncthreads();
    const int base = blockIdx.x * 4096;
#pragma unroll
    for (int k = 0; k < 16; ++k) {
      int e = base + k * 256 + tid;
      if (e < a.E) atomicAdd(&hb[a.ei[a.E + e] >> a.shift], 1);
    }
    __syncthreads();
    if (tid < a.nbkt && hb[tid] > 0) atomicAdd(&a.bcnt[tid], hb[tid]);
  }

  if (gtid < a.GH) a.pooled[gtid] = 0x007FFFFFu;  // enc(-inf)

  if (gtid < 61440) {
    int l = gtid / 20480, rem = gtid % 20480;
    int n = rem / 160, k = rem % 160;
    const float* W = (l == 0) ? a.w01 : ((l == 1) ? a.w11 : a.w21);
    int K = (l == 0) ? 66 : 130;
    float v = (k < K) ? W[(size_t)k * 128 + n] : 0.0f;
    a.Wt[gtid] = f2us(v);
  } else if (gtid < 110592) {
    int idx2 = gtid - 61440;
    int l = idx2 / 16384, rem = idx2 % 16384;
    int n = rem / 128, k = rem % 128;
    const float* W = (l == 0) ? a.w02 : ((l == 1) ? a.w12 : a.w22);
    a.Wt[gtid] = f2us(W[(size_t)k * 128 + n]);
  } else if (gtid < 110592 + 768) {
    // relu((acc+b)*g*BN_INV + e) == relu(acc*sc + c), c = b*sc + e
    int idx = gtid - 110592;
    int col = idx & 127, stage = (idx >> 7) & 1, l = idx >> 8;
    const float *bb, *gg, *ee;
    if (l == 0)      { if (!stage) { bb = a.b01; gg = a.g01; ee = a.e01; } else { bb = a.b02; gg = a.g02; ee = a.e02; } }
    else if (l == 1) { if (!stage) { bb = a.b11; gg = a.g11; ee = a.e11; } else { bb = a.b12; gg = a.g12; ee = a.e12; } }
    else             { if (!stage) { bb = a.b21; gg = a.g21; ee = a.e21; } else { bb = a.b22; gg = a.g22; ee = a.e22; } }
    float s = gg[col] * BN_INV;
    a.Ep[l * 512 + stage * 256 + col] = s;
    a.Ep[l * 512 + stage * 256 + 128 + col] = bb[col] * s + ee[col];
  }

  // concat0 (wave per row): 0..63 = x, 64..65 = pos, 66..127 = 0,
  // 128..129 = pos (persistent across layers), 130..135 = 0
  int r = gtid >> 6;
  if (r < a.N) {
    int lane = gtid & 63;
    a.h0[(size_t)r * RB + lane] = f2us(a.x[(size_t)r * 64 + lane]);
    float pv = (lane < 2) ? a.pos[(size_t)r * 2 + lane] : 0.0f;
    a.h0[(size_t)r * RB + 64 + lane] = f2us(pv);
    if (lane < 8) {
      a.h0[(size_t)r * RB + 128 + lane] = f2us((lane < 2) ? a.pos[(size_t)r * 2 + lane] : 0.0f);
    }
  }
}

// ================= neighbor max aggregation (fp16, packed, 8-deep, interleaved) =========
__global__ __launch_bounds__(256) void k_agg(
    const unsigned short* __restrict__ hcat, const int* __restrict__ rowptr,
    const int* __restrict__ eidx, unsigned short* __restrict__ z,
    int actA, int doTail, int N, int nwg) {
  const int blk = xcd_swz(blockIdx.x, nwg);
  int wid = (int)((blk * 256 + threadIdx.x) >> 6);
  if (wid >= N) return;
  const int lane = threadIdx.x & 63;
  const int half = lane >> 5;
  const int lc = lane & 31;
  const bool act = (lc < actA) || (doTail && lc == 16);
  const int cb = lc * 8;   // fp16 col base

  const unsigned NEGINF = 0xFC00FC00u;
  unsigned m0 = NEGINF, m1 = NEGINF, m2 = NEGINF, m3 = NEGINF;

  int r0 = rowptr[wid], r1 = rowptr[wid + 1];
  int e = r0 + half;
  for (; e + 14 < r1; e += 16) {  // 8 gathers in flight per half
    int s0 = eidx[e],      s1 = eidx[e + 2],  s2 = eidx[e + 4],  s3 = eidx[e + 6];
    int s4 = eidx[e + 8],  s5 = eidx[e + 10], s6 = eidx[e + 12], s7 = eidx[e + 14];
    if (act) {
      uint4 v0 = *(const uint4*)(hcat + (size_t)s0 * RB + cb);
      uint4 v1 = *(const uint4*)(hcat + (size_t)s1 * RB + cb);
      uint4 v2 = *(const uint4*)(hcat + (size_t)s2 * RB + cb);
      uint4 v3 = *(const uint4*)(hcat + (size_t)s3 * RB + cb);
      uint4 v4 = *(const uint4*)(hcat + (size_t)s4 * RB + cb);
      uint4 v5 = *(const uint4*)(hcat + (size_t)s5 * RB + cb);
      uint4 v6 = *(const uint4*)(hcat + (size_t)s6 * RB + cb);
      uint4 v7 = *(const uint4*)(hcat + (size_t)s7 * RB + cb);
      m0 = pkmax(m0, pkmax(pkmax(pkmax(v0.x, v1.x), pkmax(v2.x, v3.x)),
                           pkmax(pkmax(v4.x, v5.x), pkmax(v6.x, v7.x))));
      m1 = pkmax(m1, pkmax(pkmax(pkmax(v0.y, v1.y), pkmax(v2.y, v3.y)),
                           pkmax(pkmax(v4.y, v5.y), pkmax(v6.y, v7.y))));
      m2 = pkmax(m2, pkmax(pkmax(pkmax(v0.z, v1.z), pkmax(v2.z, v3.z)),
                           pkmax(pkmax(v4.z, v5.z), pkmax(v6.z, v7.z))));
      m3 = pkmax(m3, pkmax(pkmax(pkmax(v0.w, v1.w), pkmax(v2.w, v3.w)),
                           pkmax(pkmax(v4.w, v5.w), pkmax(v6.w, v7.w))));
    }
  }
  for (; e < r1; e += 2) {
    int s = eidx[e];
    if (act) {
      uint4 va = *(const uint4*)(hcat + (size_t)s * RB + cb);
      m0 = pkmax(m0, va.x);
      m1 = pkmax(m1, va.y);
      m2 = pkmax(m2, va.z);
      m3 = pkmax(m3, va.w);
    }
  }

  m0 = pkmax(m0, (unsigned)__shfl_xor((int)m0, 32));
  m1 = pkmax(m1, (unsigned)__shfl_xor((int)m1, 32));
  m2 = pkmax(m2, (unsigned)__shfl_xor((int)m2, 32));
  m3 = pkmax(m3, (unsigned)__shfl_xor((int)m3, 32));

  if (half == 0 && act) {
    if (r0 == r1) { m0 = 0u; m1 = 0u; m2 = 0u; m3 = 0u; }  // empty neighborhood -> 0
    uint4 sv = *(const uint4*)(hcat + (size_t)wid * RB + cb);
    uint4 o;
    o.x = pkadd(sv.x, m0);
    o.y = pkadd(sv.y, m1);
    o.z = pkadd(sv.z, m2);
    o.w = pkadd(sv.w, m3);
    *(uint4*)(z + (size_t)wid * RB + cb) = o;
  }
}

// ================= fused MFMA MLP (fp16 in, f32 accum) =================
__global__ __launch_bounds__(256) void k_mlp(
    const unsigned short* __restrict__ z, int kc1, int ntot, int nreal,
    const unsigned short* __restrict__ Wt1, const float* __restrict__ Ep1,
    const unsigned short* __restrict__ Wt2, const float* __restrict__ Ep2,
    unsigned short* __restrict__ out, const int* __restrict__ batch,
    unsigned* __restrict__ pooled, int doPool, int N, int nwg) {
  __shared__ __align__(16) unsigned short zs[4][16][ZS];
  __shared__ int bid_s[64];
  const int tid = threadIdx.x;
  const int blk = xcd_swz(blockIdx.x, nwg);
  const int w = tid >> 6, lane = tid & 63;
  const int arow = lane & 15;
  const int grp  = lane >> 4;
  const int brow0 = blk * 64;
  const int row0 = brow0 + w * 16;

  for (int c = lane; c < 16 * ntot; c += 64) {
    int r = c / ntot, seg = c - r * ntot;
    uint4 v = make_uint4(0u, 0u, 0u, 0u);
    if (seg < nreal) {
      int gr = row0 + r;
      if (gr >= N) gr = N - 1;   // clamp: reads in-bounds; writes guarded below
      v = *(const uint4*)(z + (size_t)gr * RB + seg * 8);
    }
    *(uint4*)(&zs[w][r][seg * 8]) = v;
  }

  float4v acc[8];
#pragma unroll
  for (int i = 0; i < 8; ++i) acc[i] = (float4v){0.f, 0.f, 0.f, 0.f};

  // ---- GEMM1: kc1*32 wide (zero-padded K; Wt1 stride 160) ----
  for (int kc = 0; kc < kc1; ++kc) {
    half8v a = *(const half8v*)(&zs[w][arow][kc * 32 + grp * 8]);
    const unsigned short* wp = Wt1 + (size_t)arow * 160 + kc * 32 + grp * 8;
#pragma unroll
    for (int nt = 0; nt < 8; ++nt) {
      half8v b = *(const half8v*)(wp + (size_t)(nt * 16) * 160);
      acc[nt] = __builtin_amdgcn_mfma_f32_16x16x32_f16(a, b, acc[nt], 0, 0, 0);
    }
  }

  // ---- epilogue 1 -> h1 overwrites zs (cols 0..127; same-wave producer/consumer) ----
#pragma unroll
  for (int nt = 0; nt < 8; ++nt) {
    int col = nt * 16 + arow;
    float sc = Ep1[col];
    float cc = Ep1[128 + col];
#pragma unroll
    for (int j = 0; j < 4; ++j) {
      float v = fmaxf(fmaf(acc[nt][j], sc, cc), 0.0f);
      zs[w][grp * 4 + j][col] = f2us(v);
    }
  }

  // ---- GEMM2: 128 x 128 ----
#pragma unroll
  for (int i = 0; i < 8; ++i) acc[i] = (float4v){0.f, 0.f, 0.f, 0.f};
  for (int kc = 0; kc < 4; ++kc) {
    half8v a = *(const half8v*)(&zs[w][arow][kc * 32 + grp * 8]);
    const unsigned short* wp = Wt2 + (size_t)arow * HDIM + kc * 32 + grp * 8;
#pragma unroll
    for (int nt = 0; nt < 8; ++nt) {
      half8v b = *(const half8v*)(wp + (size_t)(nt * 16) * HDIM);
      acc[nt] = __builtin_amdgcn_mfma_f32_16x16x32_f16(a, b, acc[nt], 0, 0, 0);
    }
  }

  // ---- epilogue 2 -> zs (same-wave) ----
#pragma unroll
  for (int nt = 0; nt < 8; ++nt) {
    int col = nt * 16 + arow;
    float sc = Ep2[col];
    float cc = Ep2[128 + col];
#pragma unroll
    for (int j = 0; j < 4; ++j) {
      float v = fmaxf(fmaf(acc[nt][j], sc, cc), 0.0f);
      zs[w][grp * 4 + j][col] = f2us(v);
    }
  }

  if (!doPool) {
    // coalesced copy-out: 16 rows x 16 segs of 16B (cols 0..127)
    for (int c = lane; c < 16 * 16; c += 64) {
      int r = c >> 4, seg = c & 15;
      int gr = row0 + r;
      if (gr < N) {
        *(uint4*)(out + (size_t)gr * RB + seg * 8) = *(const uint4*)(&zs[w][r][seg * 8]);
      }
    }
  } else {
    // fused global-max-pool straight from LDS (batch sorted within block rows)
    __syncthreads();   // all waves' zs tiles visible
    if (tid < 64) {
      int gr = brow0 + tid;
      bid_s[tid] = (gr < N) ? batch[gr] : -1;
    }
    __syncthreads();
    if (tid < 128) {
      const int c = tid;
      int curg = -1;
      float m = -INFINITY;
      for (int r = 0; r < 64; ++r) {
        int g = bid_s[r];
        if (g < 0) break;   // past N (batch sorted; trailing rows invalid)
        if (g != curg) {
          if (curg >= 0) atomicMax(&pooled[curg * HDIM + c], encf(m));
          curg = g;
          m = -INFINITY;
        }
        m = fmaxf(m, us2f(zs[r >> 4][r & 15][c]));
      }
      if (curg >= 0) atomicMax(&pooled[curg * HDIM + c], encf(m));
    }
  }
}

// ================= final linear [G,128] @ [128,2] =================
__global__ __launch_bounds__(64) void k_final(
    const unsigned* __restrict__ pooled, const float* __restrict__ wlin,
    const float* __restrict__ blin, float* __restrict__ out) {
  int g = blockIdx.x;
  int lane = threadIdx.x;
  float v0 = decf(pooled[g * HDIM + lane]);
  float v1 = decf(pooled[g * HDIM + 64 + lane]);
  if (v0 == -INFINITY) v0 = 0.0f;
  if (v1 == -INFINITY) v1 = 0.0f;
  float p0 = v0 * wlin[lane * 2 + 0] + v1 * wlin[(64 + lane) * 2 + 0];
  float p1 = v0 * wlin[lane * 2 + 1] + v1 * wlin[(64 + lane) * 2 + 1];
  for (int off = 32; off > 0; off >>= 1) {
    p0 += __shfl_down(p0, off);
    p1 += __shfl_down(p1, off);
  }
  if (lane == 0) {
    out[g * 2 + 0] = p0 + blin[0];
    out[g * 2 + 1] = p1 + blin[1];
  }
}

// ================= host launcher =================
static inline size_t ws_align(size_t x) { return (x + 511) & ~(size_t)511; }

extern "C" void kernel_launch(void* const* d_in, const int* in_sizes, int n_in,
                              void* d_out, int out_size, void* d_ws, size_t ws_size,
                              hipStream_t stream) {
  const float* x     = (const float*)d_in[0];
  const float* pos   = (const float*)d_in[1];
  const int*   ei    = (const int*)d_in[2];
  const int*   batch = (const int*)d_in[3];
  const float* wlin  = (const float*)d_in[28];
  const float* blin  = (const float*)d_in[29];

  const int N = in_sizes[3];
  const int E = in_sizes[2] / 2;
  const int G = out_size / 2;

  int shift = 9;
  while ((((N - 1) >> shift) + 1) > 256) ++shift;
  const int nbkt = ((N - 1) >> shift) + 1;
  const int chunks4 = (E + 4095) / 4096;   // prep histogram geometry
  const int chunks8 = (E + 8191) / 8192;   // bscatter geometry

  char* w = (char*)d_ws;
  size_t off = 0;
  auto take = [&](size_t bytes) { void* p = w + off; off += ws_align(bytes); return p; };
  int*            rowptr = (int*)take((size_t)(N + 1) * 4);
  int*            bcnt   = (int*)take(1024);
  int*            bbase  = (int*)take(2048);
  int*            gcur   = (int*)take(1024);
  int*            eidx   = (int*)take((size_t)E * 4);
  unsigned long long* sorted = (unsigned long long*)take((size_t)E * 8);
  unsigned short* hcat   = (unsigned short*)take((size_t)N * RB * 2 + 1024);
  unsigned short* z      = (unsigned short*)take((size_t)N * RB * 2 + 1024);
  unsigned short* Wt     = (unsigned short*)take((size_t)110592 * 2);
  float*          Ep     = (float*)take(3 * 2 * 2 * 128 * 4);
  unsigned*       pooled = (unsigned*)take((size_t)G * HDIM * 4);
  (void)ws_size;

  // ---- merged prep (concat0 + weights + Ep + pool init + CSR bucket histogram) ----
  hipMemsetAsync(bcnt, 0, 1024, stream);
  {
    PrepArgs a;
    a.x = x; a.pos = pos;
    a.w01 = (const float*)d_in[4];  a.w11 = (const float*)d_in[12]; a.w21 = (const float*)d_in[20];
    a.w02 = (const float*)d_in[8];  a.w12 = (const float*)d_in[16]; a.w22 = (const float*)d_in[24];
    a.b01 = (const float*)d_in[5];  a.g01 = (const float*)d_in[6];  a.e01 = (const float*)d_in[7];
    a.b02 = (const float*)d_in[9];  a.g02 = (const float*)d_in[10]; a.e02 = (const float*)d_in[11];
    a.b11 = (const float*)d_in[13]; a.g11 = (const float*)d_in[14]; a.e11 = (const float*)d_in[15];
    a.b12 = (const float*)d_in[17]; a.g12 = (const float*)d_in[18]; a.e12 = (const float*)d_in[19];
    a.b21 = (const float*)d_in[21]; a.g21 = (const float*)d_in[22]; a.e21 = (const float*)d_in[23];
    a.b22 = (const float*)d_in[25]; a.g22 = (const float*)d_in[26]; a.e22 = (const float*)d_in[27];
    a.ei = ei; a.bcnt = bcnt;
    a.h0 = hcat; a.Wt = Wt; a.pooled = pooled; a.Ep = Ep;
    a.N = N; a.GH = G * HDIM; a.E = E; a.shift = shift; a.nbkt = nbkt; a.chunks = chunks4;
    k_prep<<<(N + 3) / 4, 256, 0, stream>>>(a);
  }

  // ---- build CSR by dst ----
  k_bscan<<<1, 256, 0, stream>>>(bcnt, bbase, gcur, nbkt, E);
  k_bscatter<<<chunks8, 256, 0, stream>>>(ei, gcur, sorted, E, shift, nbkt);
  k_bcsr<<<nbkt, 512, 0, stream>>>(sorted, bbase, rowptr, eidx, shift, nbkt, N, E);

  // layer 0: gather cols 0..71 (K=66). layer 1: + cols 128..135 (pos -> z tail).
  // layer 2: z[128..135] reused from layer 1 (pos is layer-invariant).
  const int actA[3]   = {9, 16, 16};
  const int doTail[3] = {0, 1, 0};
  const int kc1a[3]   = {3, 5, 5};
  const int ntotA[3]  = {12, 21, 21};  // LDS segs staged (incl zero-fill)
  const int nrealA[3] = {12, 17, 17};  // segs actually read from z
  const int aggBlocks = (N + 3) / 4;
  const int mlpBlocks = (N + 63) / 64;

  for (int l = 0; l < 3; ++l) {
    const unsigned short* Wt1 = Wt + (size_t)l * 20480;
    const unsigned short* Wt2 = Wt + 61440 + (size_t)l * 16384;
    const float* Ep1 = Ep + l * 512;
    const float* Ep2 = Ep + l * 512 + 256;

    k_agg<<<aggBlocks, 256, 0, stream>>>(hcat, rowptr, eidx, z, actA[l], doTail[l],
                                         N, aggBlocks);
    k_mlp<<<mlpBlocks, 256, 0, stream>>>(z, kc1a[l], ntotA[l], nrealA[l],
                                         Wt1, Ep1, Wt2, Ep2, hcat, batch, pooled,
                                         (l == 2) ? 1 : 0, N, mlpBlocks);
  }

  // ---- final linear ----
  k_final<<<G, 64, 0, stream>>>(pooled, wlin, blin, (float*)d_out);
}

// Round 17
// 456.163 us; speedup vs baseline: 1.0392x; 1.0392x over previous
//
#include <hip/hip_runtime.h>
#include <hip/hip_fp16.h>
#include <math.h>
#include <string.h>

// ---------------- constants ----------------
constexpr int HDIM = 128;     // hidden width
constexpr int RB   = 136;     // fp16 row stride for hcat/z (272B) -- empirically fastest gather
constexpr int ZS   = 168;     // LDS z-tile stride (336B)
constexpr float BN_INV = 0.99999500003749980f; // 1/sqrt(1+1e-5)

typedef _Float16 half8v __attribute__((ext_vector_type(8)));  // 8 fp16 (4 VGPR)
typedef __attribute__((ext_vector_type(4))) float float4v;    // MFMA accum

// packed fp16 ops on raw u32 pairs (VOP3P)
__device__ __forceinline__ unsigned pkmax(unsigned a, unsigned b) {
  unsigned r;
  asm volatile("v_pk_max_f16 %0, %1, %2" : "=v"(r) : "v"(a), "v"(b));
  return r;
}
__device__ __forceinline__ unsigned pkadd(unsigned a, unsigned b) {
  unsigned r;
  asm volatile("v_pk_add_f16 %0, %1, %2" : "=v"(r) : "v"(a), "v"(b));
  return r;
}

__device__ __forceinline__ float us2f(unsigned short u) { __half h; memcpy(&h, &u, 2); return __half2float(h); }
__device__ __forceinline__ unsigned short f2us(float f) {
  __half h = __float2half(f); unsigned short u; memcpy(&u, &h, 2); return u;
}

// monotone float<->uint encoding for atomic max on floats
__device__ __forceinline__ unsigned encf(float f) {
  unsigned u = __float_as_uint(f);
  return (u & 0x80000000u) ? ~u : (u | 0x80000000u);
}
__device__ __forceinline__ float decf(unsigned u) {
  return (u & 0x80000000u) ? __uint_as_float(u ^ 0x80000000u) : __uint_as_float(~u);
}

// m204 bijective XCD swizzle (heuristic; wrong mapping = only lost locality)
__device__ __forceinline__ int xcd_swz(int bid, int nwg) {
  int q = nwg >> 3, r = nwg & 7;
  int xcd = bid & 7, idx = bid >> 3;
  int base = (xcd < r) ? xcd * (q + 1) : r * (q + 1) + (xcd - r) * q;
  return base + idx;
}

// ================= CSR build (bucket-local, LDS-atomic) =================
// (bucket histogram is fused into k_prep)
__global__ __launch_bounds__(256) void k_bscan(
    const int* __restrict__ bcnt, int* __restrict__ bbase, int* __restrict__ gcur,
    int nbkt, int E) {
  __shared__ int s[256];
  int tid = threadIdx.x;
  int v = (tid < nbkt) ? bcnt[tid] : 0;
  s[tid] = v;
  __syncthreads();
  for (int off = 1; off < 256; off <<= 1) {
    int t = (tid >= off) ? s[tid - off] : 0;
    __syncthreads();
    s[tid] += t;
    __syncthreads();
  }
  if (tid < nbkt) {
    int e = s[tid] - v;
    bbase[tid] = e;
    gcur[tid] = e;
  }
  if (tid == 0) bbase[nbkt] = E;
}

// phase A: 8192-edge chunks (64KB sbuf, 2 blocks/CU) -> longer coalesced runs on flush
__global__ __launch_bounds__(256) void k_bscatter(
    const int* __restrict__ ei, int* __restrict__ gcur,
    unsigned long long* __restrict__ sorted, int E, int shift, int nbkt) {
  __shared__ int hcnt[256];
  __shared__ int hstart[256];
  __shared__ int gbase[256];
  __shared__ unsigned long long sbuf[8192];  // 64 KB

  const int tid = threadIdx.x;
  const int base = blockIdx.x * 8192;
  const int validCount = min(8192, E - base);

  hcnt[tid] = 0;
  __syncthreads();

  int sArr[32], dArr[32];
#pragma unroll
  for (int k = 0; k < 32; ++k) {
    int e = base + k * 256 + tid;
    if (e < E) {
      sArr[k] = ei[e];
      dArr[k] = ei[E + e];
      atomicAdd(&hcnt[dArr[k] >> shift], 1);
    } else {
      sArr[k] = -1; dArr[k] = -1;
    }
  }
  __syncthreads();

  {
    int v = hcnt[tid];
    __shared__ int sc[256];
    sc[tid] = v;
    __syncthreads();
    for (int off = 1; off < 256; off <<= 1) {
      int t = (tid >= off) ? sc[tid - off] : 0;
      __syncthreads();
      sc[tid] += t;
      __syncthreads();
    }
    hstart[tid] = sc[tid] - v;
    if (tid < nbkt && v > 0) gbase[tid] = atomicAdd(&gcur[tid], v);
    hcnt[tid] = sc[tid] - v;
  }
  __syncthreads();

#pragma unroll
  for (int k = 0; k < 32; ++k) {
    if (dArr[k] >= 0) {
      int b = dArr[k] >> shift;
      int p = atomicAdd(&hcnt[b], 1);
      sbuf[p] = ((unsigned long long)(unsigned)dArr[k] << 32) | (unsigned)sArr[k];
    }
  }
  __syncthreads();

  for (int p = tid; p < validCount; p += 256) {
    unsigned long long v = sbuf[p];
    int b = (int)(v >> 32) >> shift;
    sorted[(size_t)gbase[b] + (p - hstart[b])] = v;
  }
}

// phase B: one 512-thread block per bucket -> rowptr + eidx scatter (cursors in LDS)
__global__ __launch_bounds__(512) void k_bcsr(
    const unsigned long long* __restrict__ sorted, const int* __restrict__ bbase,
    int* __restrict__ rowptr, int* __restrict__ eidx,
    int shift, int nbkt, int N, int E) {
  __shared__ int cnt[512];
  __shared__ int sc[512];
  const int b = blockIdx.x, tid = threadIdx.x;
  const int nodeBase = b << shift;
  const int nodesHere = min(512, N - nodeBase);
  const int lo = bbase[b], hi = bbase[b + 1];

  cnt[tid] = 0;
  __syncthreads();
  for (int i = lo + tid; i < hi; i += 512) {
    int d = (int)(sorted[i] >> 32);
    atomicAdd(&cnt[d - nodeBase], 1);
  }
  __syncthreads();
  int v = cnt[tid];
  sc[tid] = v;
  __syncthreads();
  for (int off = 1; off < 512; off <<= 1) {
    int t = (tid >= off) ? sc[tid - off] : 0;
    __syncthreads();
    sc[tid] += t;
    __syncthreads();
  }
  int excl = sc[tid] - v;
  if (tid < nodesHere) rowptr[nodeBase + tid] = lo + excl;
  cnt[tid] = excl;  // reset as running cursor
  if (b == nbkt - 1 && tid == 0) rowptr[N] = E;
  __syncthreads();
  for (int i = lo + tid; i < hi; i += 512) {
    unsigned long long vv = sorted[i];
    int d = (int)(vv >> 32);
    int s = (int)(vv & 0xFFFFFFFFu);
    int p = atomicAdd(&cnt[d - nodeBase], 1);
    eidx[lo + p] = s;
  }
}

// ================= merged prep (+ fused bucket histogram) =================
struct PrepArgs {
  const float *x, *pos;
  const float *w01, *w11, *w21, *w02, *w12, *w22;
  const float *b01, *g01, *e01, *b02, *g02, *e02;
  const float *b11, *g11, *e11, *b12, *g12, *e12;
  const float *b21, *g21, *e21, *b22, *g22, *e22;
  const int *ei;
  int *bcnt;
  unsigned short *h0;    // [N][RB] interleaved
  unsigned short *Wt;
  unsigned *pooled;
  float *Ep;             // [3][2][2][128]
  int N, GH, E, shift, nbkt, chunks;
};

__global__ __launch_bounds__(256) void k_prep(PrepArgs a) {
  __shared__ int hb[256];
  const int tid = threadIdx.x;
  const int gtid = blockIdx.x * 256 + tid;

  // ---- fused CSR bucket histogram (blocks < chunks; 4096 edges/block) ----
  if (blockIdx.x < a.chunks) {
    hb[tid] = 0;
    __syncthreads();
    const int base = blockIdx.x * 4096;
#pragma unroll
    for (int k = 0; k < 16; ++k) {
      int e = base + k * 256 + tid;
      if (e < a.E) atomicAdd(&hb[a.ei[a.E + e] >> a.shift], 1);
    }
    __syncthreads();
    if (tid < a.nbkt && hb[tid] > 0) atomicAdd(&a.bcnt[tid], hb[tid]);
  }

  if (gtid < a.GH) a.pooled[gtid] = 0x007FFFFFu;  // enc(-inf)

  if (gtid < 61440) {
    int l = gtid / 20480, rem = gtid % 20480;
    int n = rem / 160, k = rem % 160;
    const float* W = (l == 0) ? a.w01 : ((l == 1) ? a.w11 : a.w21);
    int K = (l == 0) ? 66 : 130;
    float v = (k < K) ? W[(size_t)k * 128 + n] : 0.0f;
    a.Wt[gtid] = f2us(v);
  } else if (gtid < 110592) {
    int idx2 = gtid - 61440;
    int l = idx2 / 16384, rem = idx2 % 16384;
    int n = rem / 128, k = rem % 128;
    const float* W = (l == 0) ? a.w02 : ((l == 1) ? a.w12 : a.w22);
    a.Wt[gtid] = f2us(W[(size_t)k * 128 + n]);
  } else if (gtid < 110592 + 768) {
    // relu((acc+b)*g*BN_INV + e) == relu(acc*sc + c), c = b*sc + e
    int idx = gtid - 110592;
    int col = idx & 127, stage = (idx >> 7) & 1, l = idx >> 8;
    const float *bb, *gg, *ee;
    if (l == 0)      { if (!stage) { bb = a.b01; gg = a.g01; ee = a.e01; } else { bb = a.b02; gg = a.g02; ee = a.e02; } }
    else if (l == 1) { if (!stage) { bb = a.b11; gg = a.g11; ee = a.e11; } else { bb = a.b12; gg = a.g12; ee = a.e12; } }
    else             { if (!stage) { bb = a.b21; gg = a.g21; ee = a.e21; } else { bb = a.b22; gg = a.g22; ee = a.e22; } }
    float s = gg[col] * BN_INV;
    a.Ep[l * 512 + stage * 256 + col] = s;
    a.Ep[l * 512 + stage * 256 + 128 + col] = bb[col] * s + ee[col];
  }

  // concat0 (wave per row): 0..63 = x, 64..65 = pos, 66..127 = 0,
  // 128..129 = pos (persistent across layers), 130..135 = 0
  int r = gtid >> 6;
  if (r < a.N) {
    int lane = gtid & 63;
    a.h0[(size_t)r * RB + lane] = f2us(a.x[(size_t)r * 64 + lane]);
    float pv = (lane < 2) ? a.pos[(size_t)r * 2 + lane] : 0.0f;
    a.h0[(size_t)r * RB + 64 + lane] = f2us(pv);
    if (lane < 8) {
      a.h0[(size_t)r * RB + 128 + lane] = f2us((lane < 2) ? a.pos[(size_t)r * 2 + lane] : 0.0f);
    }
  }
}

// ================= neighbor max aggregation (fp16, packed, 4-deep, interleaved) =========
// Empirically optimal depth: 2-deep=86us, 4-deep=83us, 8-deep=87us (VGPR/occupancy).
__global__ __launch_bounds__(256) void k_agg(
    const unsigned short* __restrict__ hcat, const int* __restrict__ rowptr,
    const int* __restrict__ eidx, unsigned short* __restrict__ z,
    int actA, int doTail, int N, int nwg) {
  const int blk = xcd_swz(blockIdx.x, nwg);
  int wid = (int)((blk * 256 + threadIdx.x) >> 6);
  if (wid >= N) return;
  const int lane = threadIdx.x & 63;
  const int half = lane >> 5;
  const int lc = lane & 31;
  const bool act = (lc < actA) || (doTail && lc == 16);
  const int cb = lc * 8;   // fp16 col base

  const unsigned NEGINF = 0xFC00FC00u;
  unsigned m0 = NEGINF, m1 = NEGINF, m2 = NEGINF, m3 = NEGINF;

  int r0 = rowptr[wid], r1 = rowptr[wid + 1];
  int e = r0 + half;
  for (; e + 6 < r1; e += 8) {   // 4 gathers in flight per half
    int s0 = eidx[e], s1 = eidx[e + 2], s2 = eidx[e + 4], s3 = eidx[e + 6];
    if (act) {
      uint4 v0 = *(const uint4*)(hcat + (size_t)s0 * RB + cb);
      uint4 v1 = *(const uint4*)(hcat + (size_t)s1 * RB + cb);
      uint4 v2 = *(const uint4*)(hcat + (size_t)s2 * RB + cb);
      uint4 v3 = *(const uint4*)(hcat + (size_t)s3 * RB + cb);
      m0 = pkmax(m0, pkmax(pkmax(v0.x, v1.x), pkmax(v2.x, v3.x)));
      m1 = pkmax(m1, pkmax(pkmax(v0.y, v1.y), pkmax(v2.y, v3.y)));
      m2 = pkmax(m2, pkmax(pkmax(v0.z, v1.z), pkmax(v2.z, v3.z)));
      m3 = pkmax(m3, pkmax(pkmax(v0.w, v1.w), pkmax(v2.w, v3.w)));
    }
  }
  for (; e < r1; e += 2) {
    int s = eidx[e];
    if (act) {
      uint4 va = *(const uint4*)(hcat + (size_t)s * RB + cb);
      m0 = pkmax(m0, va.x);
      m1 = pkmax(m1, va.y);
      m2 = pkmax(m2, va.z);
      m3 = pkmax(m3, va.w);
    }
  }

  m0 = pkmax(m0, (unsigned)__shfl_xor((int)m0, 32));
  m1 = pkmax(m1, (unsigned)__shfl_xor((int)m1, 32));
  m2 = pkmax(m2, (unsigned)__shfl_xor((int)m2, 32));
  m3 = pkmax(m3, (unsigned)__shfl_xor((int)m3, 32));

  if (half == 0 && act) {
    if (r0 == r1) { m0 = 0u; m1 = 0u; m2 = 0u; m3 = 0u; }  // empty neighborhood -> 0
    uint4 sv = *(const uint4*)(hcat + (size_t)wid * RB + cb);
    uint4 o;
    o.x = pkadd(sv.x, m0);
    o.y = pkadd(sv.y, m1);
    o.z = pkadd(sv.z, m2);
    o.w = pkadd(sv.w, m3);
    *(uint4*)(z + (size_t)wid * RB + cb) = o;
  }
}

// ================= fused MFMA MLP (fp16 in, f32 accum) =================
__global__ __launch_bounds__(256) void k_mlp(
    const unsigned short* __restrict__ z, int kc1, int ntot, int nreal,
    const unsigned short* __restrict__ Wt1, const float* __restrict__ Ep1,
    const unsigned short* __restrict__ Wt2, const float* __restrict__ Ep2,
    unsigned short* __restrict__ out, const int* __restrict__ batch,
    unsigned* __restrict__ pooled, int doPool, int N, int nwg) {
  __shared__ __align__(16) unsigned short zs[4][16][ZS];
  __shared__ int bid_s[64];
  const int tid = threadIdx.x;
  const int blk = xcd_swz(blockIdx.x, nwg);
  const int w = tid >> 6, lane = tid & 63;
  const int arow = lane & 15;
  const int grp  = lane >> 4;
  const int brow0 = blk * 64;
  const int row0 = brow0 + w * 16;

  for (int c = lane; c < 16 * ntot; c += 64) {
    int r = c / ntot, seg = c - r * ntot;
    uint4 v = make_uint4(0u, 0u, 0u, 0u);
    if (seg < nreal) {
      int gr = row0 + r;
      if (gr >= N) gr = N - 1;   // clamp: reads in-bounds; writes guarded below
      v = *(const uint4*)(z + (size_t)gr * RB + seg * 8);
    }
    *(uint4*)(&zs[w][r][seg * 8]) = v;
  }

  float4v acc[8];
#pragma unroll
  for (int i = 0; i < 8; ++i) acc[i] = (float4v){0.f, 0.f, 0.f, 0.f};

  // ---- GEMM1: kc1*32 wide (zero-padded K; Wt1 stride 160) ----
  for (int kc = 0; kc < kc1; ++kc) {
    half8v a = *(const half8v*)(&zs[w][arow][kc * 32 + grp * 8]);
    const unsigned short* wp = Wt1 + (size_t)arow * 160 + kc * 32 + grp * 8;
#pragma unroll
    for (int nt = 0; nt < 8; ++nt) {
      half8v b = *(const half8v*)(wp + (size_t)(nt * 16) * 160);
      acc[nt] = __builtin_amdgcn_mfma_f32_16x16x32_f16(a, b, acc[nt], 0, 0, 0);
    }
  }

  // ---- epilogue 1 -> h1 overwrites zs (cols 0..127; same-wave producer/consumer) ----
#pragma unroll
  for (int nt = 0; nt < 8; ++nt) {
    int col = nt * 16 + arow;
    float sc = Ep1[col];
    float cc = Ep1[128 + col];
#pragma unroll
    for (int j = 0; j < 4; ++j) {
      float v = fmaxf(fmaf(acc[nt][j], sc, cc), 0.0f);
      zs[w][grp * 4 + j][col] = f2us(v);
    }
  }

  // ---- GEMM2: 128 x 128 ----
#pragma unroll
  for (int i = 0; i < 8; ++i) acc[i] = (float4v){0.f, 0.f, 0.f, 0.f};
  for (int kc = 0; kc < 4; ++kc) {
    half8v a = *(const half8v*)(&zs[w][arow][kc * 32 + grp * 8]);
    const unsigned short* wp = Wt2 + (size_t)arow * HDIM + kc * 32 + grp * 8;
#pragma unroll
    for (int nt = 0; nt < 8; ++nt) {
      half8v b = *(const half8v*)(wp + (size_t)(nt * 16) * HDIM);
      acc[nt] = __builtin_amdgcn_mfma_f32_16x16x32_f16(a, b, acc[nt], 0, 0, 0);
    }
  }

  // ---- epilogue 2 -> zs (same-wave) ----
#pragma unroll
  for (int nt = 0; nt < 8; ++nt) {
    int col = nt * 16 + arow;
    float sc = Ep2[col];
    float cc = Ep2[128 + col];
#pragma unroll
    for (int j = 0; j < 4; ++j) {
      float v = fmaxf(fmaf(acc[nt][j], sc, cc), 0.0f);
      zs[w][grp * 4 + j][col] = f2us(v);
    }
  }

  if (!doPool) {
    // coalesced copy-out: 16 rows x 16 segs of 16B (cols 0..127)
    for (int c = lane; c < 16 * 16; c += 64) {
      int r = c >> 4, seg = c & 15;
      int gr = row0 + r;
      if (gr < N) {
        *(uint4*)(out + (size_t)gr * RB + seg * 8) = *(const uint4*)(&zs[w][r][seg * 8]);
      }
    }
  } else {
    // fused global-max-pool straight from LDS (batch sorted within block rows)
    __syncthreads();   // all waves' zs tiles visible
    if (tid < 64) {
      int gr = brow0 + tid;
      bid_s[tid] = (gr < N) ? batch[gr] : -1;
    }
    __syncthreads();
    if (tid < 128) {
      const int c = tid;
      int curg = -1;
      float m = -INFINITY;
      for (int r = 0; r < 64; ++r) {
        int g = bid_s[r];
        if (g < 0) break;   // past N (batch sorted; trailing rows invalid)
        if (g != curg) {
          if (curg >= 0) atomicMax(&pooled[curg * HDIM + c], encf(m));
          curg = g;
          m = -INFINITY;
        }
        m = fmaxf(m, us2f(zs[r >> 4][r & 15][c]));
      }
      if (curg >= 0) atomicMax(&pooled[curg * HDIM + c], encf(m));
    }
  }
}

// ================= final linear [G,128] @ [128,2] =================
__global__ __launch_bounds__(64) void k_final(
    const unsigned* __restrict__ pooled, const float* __restrict__ wlin,
    const float* __restrict__ blin, float* __restrict__ out) {
  int g = blockIdx.x;
  int lane = threadIdx.x;
  float v0 = decf(pooled[g * HDIM + lane]);
  float v1 = decf(pooled[g * HDIM + 64 + lane]);
  if (v0 == -INFINITY) v0 = 0.0f;
  if (v1 == -INFINITY) v1 = 0.0f;
  float p0 = v0 * wlin[lane * 2 + 0] + v1 * wlin[(64 + lane) * 2 + 0];
  float p1 = v0 * wlin[lane * 2 + 1] + v1 * wlin[(64 + lane) * 2 + 1];
  for (int off = 32; off > 0; off >>= 1) {
    p0 += __shfl_down(p0, off);
    p1 += __shfl_down(p1, off);
  }
  if (lane == 0) {
    out[g * 2 + 0] = p0 + blin[0];
    out[g * 2 + 1] = p1 + blin[1];
  }
}

// ================= host launcher =================
static inline size_t ws_align(size_t x) { return (x + 511) & ~(size_t)511; }

extern "C" void kernel_launch(void* const* d_in, const int* in_sizes, int n_in,
                              void* d_out, int out_size, void* d_ws, size_t ws_size,
                              hipStream_t stream) {
  const float* x     = (const float*)d_in[0];
  const float* pos   = (const float*)d_in[1];
  const int*   ei    = (const int*)d_in[2];
  const int*   batch = (const int*)d_in[3];
  const float* wlin  = (const float*)d_in[28];
  const float* blin  = (const float*)d_in[29];

  const int N = in_sizes[3];
  const int E = in_sizes[2] / 2;
  const int G = out_size / 2;

  int shift = 9;
  while ((((N - 1) >> shift) + 1) > 256) ++shift;
  const int nbkt = ((N - 1) >> shift) + 1;
  const int chunks4 = (E + 4095) / 4096;   // prep histogram geometry
  const int chunks8 = (E + 8191) / 8192;   // bscatter geometry

  char* w = (char*)d_ws;
  size_t off = 0;
  auto take = [&](size_t bytes) { void* p = w + off; off += ws_align(bytes); return p; };
  int*            rowptr = (int*)take((size_t)(N + 1) * 4);
  int*            bcnt   = (int*)take(1024);
  int*            bbase  = (int*)take(2048);
  int*            gcur   = (int*)take(1024);
  int*            eidx   = (int*)take((size_t)E * 4);
  unsigned long long* sorted = (unsigned long long*)take((size_t)E * 8);
  unsigned short* hcat   = (unsigned short*)take((size_t)N * RB * 2 + 1024);
  unsigned short* z      = (unsigned short*)take((size_t)N * RB * 2 + 1024);
  unsigned short* Wt     = (unsigned short*)take((size_t)110592 * 2);
  float*          Ep     = (float*)take(3 * 2 * 2 * 128 * 4);
  unsigned*       pooled = (unsigned*)take((size_t)G * HDIM * 4);
  (void)ws_size;

  // ---- merged prep (concat0 + weights + Ep + pool init + CSR bucket histogram) ----
  hipMemsetAsync(bcnt, 0, 1024, stream);
  {
    PrepArgs a;
    a.x = x; a.pos = pos;
    a.w01 = (const float*)d_in[4];  a.w11 = (const float*)d_in[12]; a.w21 = (const float*)d_in[20];
    a.w02 = (const float*)d_in[8];  a.w12 = (const float*)d_in[16]; a.w22 = (const float*)d_in[24];
    a.b01 = (const float*)d_in[5];  a.g01 = (const float*)d_in[6];  a.e01 = (const float*)d_in[7];
    a.b02 = (const float*)d_in[9];  a.g02 = (const float*)d_in[10]; a.e02 = (const float*)d_in[11];
    a.b11 = (const float*)d_in[13]; a.g11 = (const float*)d_in[14]; a.e11 = (const float*)d_in[15];
    a.b12 = (const float*)d_in[17]; a.g12 = (const float*)d_in[18]; a.e12 = (const float*)d_in[19];
    a.b21 = (const float*)d_in[21]; a.g21 = (const float*)d_in[22]; a.e21 = (const float*)d_in[23];
    a.b22 = (const float*)d_in[25]; a.g22 = (const float*)d_in[26]; a.e22 = (const float*)d_in[27];
    a.ei = ei; a.bcnt = bcnt;
    a.h0 = hcat; a.Wt = Wt; a.pooled = pooled; a.Ep = Ep;
    a.N = N; a.GH = G * HDIM; a.E = E; a.shift = shift; a.nbkt = nbkt; a.chunks = chunks4;
    k_prep<<<(N + 3) / 4, 256, 0, stream>>>(a);
  }

  // ---- build CSR by dst ----
  k_bscan<<<1, 256, 0, stream>>>(bcnt, bbase, gcur, nbkt, E);
  k_bscatter<<<chunks8, 256, 0, stream>>>(ei, gcur, sorted, E, shift, nbkt);
  k_bcsr<<<nbkt, 512, 0, stream>>>(sorted, bbase, rowptr, eidx, shift, nbkt, N, E);

  // layer 0: gather cols 0..71 (K=66). layer 1: + cols 128..135 (pos -> z tail).
  // layer 2: z[128..135] reused from layer 1 (pos is layer-invariant).
  const int actA[3]   = {9, 16, 16};
  const int doTail[3] = {0, 1, 0};
  const int kc1a[3]   = {3, 5, 5};
  const int ntotA[3]  = {12, 21, 21};  // LDS segs staged (incl zero-fill)
  const int nrealA[3] = {12, 17, 17};  // segs actually read from z
  const int aggBlocks = (N + 3) / 4;
  const int mlpBlocks = (N + 63) / 64;

  for (int l = 0; l < 3; ++l) {
    const unsigned short* Wt1 = Wt + (size_t)l * 20480;
    const unsigned short* Wt2 = Wt + 61440 + (size_t)l * 16384;
    const float* Ep1 = Ep + l * 512;
    const float* Ep2 = Ep + l * 512 + 256;

    k_agg<<<aggBlocks, 256, 0, stream>>>(hcat, rowptr, eidx, z, actA[l], doTail[l],
                                         N, aggBlocks);
    k_mlp<<<mlpBlocks, 256, 0, stream>>>(z, kc1a[l], ntotA[l], nrealA[l],
                                         Wt1, Ep1, Wt2, Ep2, hcat, batch, pooled,
                                         (l == 2) ? 1 : 0, N, mlpBlocks);
  }

  // ---- final linear ----
  k_final<<<G, 64, 0, stream>>>(pooled, wlin, blin, (float*)d_out);
}